// Round 1
// baseline (1174.009 us; speedup 1.0000x reference)
//
#include <hip/hip_runtime.h>

#define Bn 8
#define Tn 2048
#define Cn 1024
#define Mn (Bn * Tn)   // 16384 rows

typedef __attribute__((ext_vector_type(8))) short short8;
typedef __attribute__((ext_vector_type(4))) float f32x4;

typedef const __attribute__((address_space(1))) void gas_void;
typedef __attribute__((address_space(3))) void las_void;

__device__ __forceinline__ unsigned short f2bf(float f) {
    unsigned int u = __float_as_uint(f);
    u += 0x7FFFu + ((u >> 16) & 1u);   // round-to-nearest-even
    return (unsigned short)(u >> 16);
}
__device__ __forceinline__ float bf2f(unsigned short h) {
    return __uint_as_float(((unsigned int)h) << 16);
}

// ---------------- weight fp32 -> bf16 convert ----------------
__global__ __launch_bounds__(256) void cvt_kernel(const float* __restrict__ src,
                                                  unsigned short* __restrict__ dst) {
    int i = blockIdx.x * 256 + threadIdx.x;           // over C*C/4 float4s
    float4 v = ((const float4*)src)[i];
    ushort4 o;
    o.x = f2bf(v.x); o.y = f2bf(v.y); o.z = f2bf(v.z); o.w = f2bf(v.w);
    ((ushort4*)dst)[i] = o;
}

// ---------------- token shift + time-mix (3 outputs, bf16) ----------------
__device__ __forceinline__ ushort4 mix4(const float4& a, const float4& s, const float4& m) {
    ushort4 o;
    o.x = f2bf(s.x + (a.x - s.x) * m.x);
    o.y = f2bf(s.y + (a.y - s.y) * m.y);
    o.z = f2bf(s.z + (a.z - s.z) * m.z);
    o.w = f2bf(s.w + (a.w - s.w) * m.w);
    return o;
}

__global__ __launch_bounds__(256) void mix_kernel(const float* __restrict__ x,
                                                  const float* __restrict__ tmk,
                                                  const float* __restrict__ tmv,
                                                  const float* __restrict__ tmr,
                                                  unsigned short* __restrict__ ak,
                                                  unsigned short* __restrict__ av,
                                                  unsigned short* __restrict__ ar) {
    int i = blockIdx.x * 256 + threadIdx.x;           // over Mn*Cn/4 float4s
    int c4 = i & 255;                                  // Cn/4 = 256
    int t  = (i >> 8) & (Tn - 1);
    float4 xc = ((const float4*)x)[i];
    float4 xs = make_float4(0.f, 0.f, 0.f, 0.f);
    if (t > 0) xs = ((const float4*)x)[i - 256];
    float4 mk = ((const float4*)tmk)[c4];
    float4 mv = ((const float4*)tmv)[c4];
    float4 mr = ((const float4*)tmr)[c4];
    ((ushort4*)ak)[i] = mix4(xc, xs, mk);
    ((ushort4*)av)[i] = mix4(xc, xs, mv);
    ((ushort4*)ar)[i] = mix4(xc, xs, mr);
}

// ---------------- bf16 NT GEMM: C[m,n] = sum_k A[m,k]*B[n,k] ----------------
// M=16384, N=1024, K=1024.  128x128 tile, BK=32, 4 waves (2x2 of 64x64).
#define BK 32

template <int FOUT>   // 0: bf16 out, 1: fp32 out
__global__ __launch_bounds__(256) void gemm_bt(const unsigned short* __restrict__ A,
                                               const unsigned short* __restrict__ Bw,
                                               unsigned short* __restrict__ Cb,
                                               float* __restrict__ Cf) {
    __shared__ unsigned short lA[128 * BK];
    __shared__ unsigned short lB[128 * BK];
    const int tid  = threadIdx.x;
    const int lane = tid & 63;
    const int wid  = tid >> 6;
    const int wr   = wid >> 1;          // wave row (0..1)
    const int wc   = wid & 1;           // wave col (0..1)
    const int bm   = blockIdx.x * 128;
    const int bn   = blockIdx.y * 128;

    const int srow = lane >> 2;         // 0..15 (staging row within 16-row chunk)
    const int scol = (lane & 3) * 8;    // 0,8,16,24 (staging col, 8 bf16 = 16B)
    const int lr   = lane & 15;         // fragment row/col
    const int lk   = (lane >> 4) * 8;   // fragment k offset within 32

    f32x4 acc[4][4] = {};

    for (int k0 = 0; k0 < 1024; k0 += BK) {
#pragma unroll
        for (int i = 0; i < 2; ++i) {
            int r = wid * 32 + i * 16;  // wave-uniform row base in tile
            const unsigned short* ga = A  + (size_t)(bm + r + srow) * 1024 + k0 + scol;
            const unsigned short* gb = Bw + (size_t)(bn + r + srow) * 1024 + k0 + scol;
            __builtin_amdgcn_global_load_lds((gas_void*)ga, (las_void*)&lA[r * BK], 16, 0, 0);
            __builtin_amdgcn_global_load_lds((gas_void*)gb, (las_void*)&lB[r * BK], 16, 0, 0);
        }
        __syncthreads();

        short8 af[4], bfv[4];
#pragma unroll
        for (int m = 0; m < 4; ++m)
            af[m] = *(const short8*)&lA[(wr * 64 + m * 16 + lr) * BK + lk];
#pragma unroll
        for (int n = 0; n < 4; ++n)
            bfv[n] = *(const short8*)&lB[(wc * 64 + n * 16 + lr) * BK + lk];
#pragma unroll
        for (int m = 0; m < 4; ++m)
#pragma unroll
            for (int n = 0; n < 4; ++n)
                acc[m][n] = __builtin_amdgcn_mfma_f32_16x16x32_bf16(af[m], bfv[n], acc[m][n], 0, 0, 0);
        __syncthreads();
    }

    // C/D layout (verified m89/m91): col = lane&15, row = (lane>>4)*4 + reg
    const int crow0 = bm + wr * 64 + (lane >> 4) * 4;
    const int ccol0 = bn + wc * 64 + (lane & 15);
#pragma unroll
    for (int m = 0; m < 4; ++m) {
#pragma unroll
        for (int n = 0; n < 4; ++n) {
            int col = ccol0 + n * 16;
#pragma unroll
            for (int j = 0; j < 4; ++j) {
                size_t idx = (size_t)(crow0 + m * 16 + j) * 1024 + col;
                float v = acc[m][n][j];
                if (FOUT) Cf[idx] = v;
                else      Cb[idx] = f2bf(v);
            }
        }
    }
}

// ---------------- WKV scan + sigmoid(R) gating ----------------
__global__ __launch_bounds__(256) void wkv_kernel(const unsigned short* __restrict__ Kb,
                                                  const unsigned short* __restrict__ Vb,
                                                  const unsigned short* __restrict__ Rb,
                                                  const float* __restrict__ Wd,
                                                  const float* __restrict__ Ud,
                                                  unsigned short* __restrict__ rwkv,
                                                  float* __restrict__ hidden) {
    int c = blockIdx.x * 256 + threadIdx.x;   // 0..1023
    int b = blockIdx.y;                        // 0..7
    float w = -__expf(Wd[c]);
    float u = Ud[c];
    float aa = 0.f, bb = 0.f, pp = -1e38f;
    size_t base = ((size_t)b * Tn) * Cn + c;
    float ylast = 0.f;
    for (int t = 0; t < Tn; ++t) {
        size_t idx = base + (size_t)t * Cn;
        float kt = bf2f(Kb[idx]);
        float vt = bf2f(Vb[idx]);
        float rt = bf2f(Rb[idx]);
        float ww = u + kt;
        float p  = fmaxf(pp, ww);
        float e1 = __expf(pp - p);
        float e2 = __expf(ww - p);
        float y  = (e1 * aa + e2 * vt) / (e1 * bb + e2);
        float sr = 1.f / (1.f + __expf(-rt));
        rwkv[idx] = f2bf(sr * y);
        ylast = y;
        float ww2 = pp + w;
        float p2  = fmaxf(ww2, kt);
        float e1b = __expf(ww2 - p2);
        float e2b = __expf(kt - p2);
        aa = e1b * aa + e2b * vt;
        bb = e1b * bb + e2b;
        pp = p2;
    }
    hidden[b * Cn + c] = ylast;
}

// ---------------- launcher ----------------
extern "C" void kernel_launch(void* const* d_in, const int* in_sizes, int n_in,
                              void* d_out, int out_size, void* d_ws, size_t ws_size,
                              hipStream_t stream) {
    const float* x   = (const float*)d_in[0];
    const float* Wd  = (const float*)d_in[1];
    const float* Ud  = (const float*)d_in[2];
    const float* tmk = (const float*)d_in[3];
    const float* tmv = (const float*)d_in[4];
    const float* tmr = (const float*)d_in[5];
    const float* Wk  = (const float*)d_in[6];
    const float* Wv  = (const float*)d_in[7];
    const float* Wr  = (const float*)d_in[8];
    const float* Wo  = (const float*)d_in[9];

    float* out    = (float*)d_out;
    float* hidden = out + (size_t)Mn * Cn;

    const size_t MK = (size_t)Mn * Cn;   // 16,777,216 elements
    const size_t CC = (size_t)Cn * Cn;   // 1,048,576 elements
    unsigned short* ak  = (unsigned short*)d_ws;   // [0, MK)
    unsigned short* av  = ak + MK;
    unsigned short* ar  = av + MK;
    unsigned short* Kb  = ar + MK;
    unsigned short* Wkb = Kb + MK;
    unsigned short* Wvb = Wkb + CC;
    unsigned short* Wrb = Wvb + CC;
    unsigned short* Wob = Wrb + CC;
    // overlays (safe by dataflow order):
    unsigned short* Vb = ak;   // ak dead after GEMM-K
    unsigned short* Rb = av;   // av dead after GEMM-V
    unsigned short* rw = ar;   // ar dead after GEMM-R

    cvt_kernel<<<dim3(CC / 1024), 256, 0, stream>>>(Wk, Wkb);
    cvt_kernel<<<dim3(CC / 1024), 256, 0, stream>>>(Wv, Wvb);
    cvt_kernel<<<dim3(CC / 1024), 256, 0, stream>>>(Wr, Wrb);
    cvt_kernel<<<dim3(CC / 1024), 256, 0, stream>>>(Wo, Wob);

    mix_kernel<<<dim3(MK / 1024), 256, 0, stream>>>(x, tmk, tmv, tmr, ak, av, ar);

    dim3 gg(Mn / 128, Cn / 128);   // (128, 8)
    gemm_bt<0><<<gg, 256, 0, stream>>>(ak, Wkb, Kb, nullptr);
    gemm_bt<0><<<gg, 256, 0, stream>>>(av, Wvb, Vb, nullptr);
    gemm_bt<0><<<gg, 256, 0, stream>>>(ar, Wrb, Rb, nullptr);

    wkv_kernel<<<dim3(Cn / 256, Bn), 256, 0, stream>>>(Kb, Vb, Rb, Wd, Ud, rw, hidden);

    gemm_bt<1><<<gg, 256, 0, stream>>>(rw, Wob, nullptr, out);
}

// Round 4
// 408.391 us; speedup vs baseline: 2.8747x; 2.8747x over previous
//
#include <hip/hip_runtime.h>

#define Bn 8
#define Tn 2048
#define Cn 1024
#define Mn (Bn * Tn)   // 16384 rows
#define LCH 64
#define NCH (Tn / LCH) // 32 chunks

typedef __attribute__((ext_vector_type(8))) short short8;
typedef __attribute__((ext_vector_type(4))) float f32x4;

typedef const __attribute__((address_space(1))) void gas_void;
typedef __attribute__((address_space(3))) void las_void;

__device__ __forceinline__ unsigned short f2bf(float f) {
    unsigned int u = __float_as_uint(f);
    u += 0x7FFFu + ((u >> 16) & 1u);   // round-to-nearest-even
    return (unsigned short)(u >> 16);
}
__device__ __forceinline__ float bf2f(unsigned short h) {
    return __uint_as_float(((unsigned int)h) << 16);
}

// ---------------- weight fp32 -> bf16 convert ----------------
__global__ __launch_bounds__(256) void cvt_kernel(const float* __restrict__ src,
                                                  unsigned short* __restrict__ dst) {
    int i = blockIdx.x * 256 + threadIdx.x;           // over C*C/4 float4s
    float4 v = ((const float4*)src)[i];
    ushort4 o;
    o.x = f2bf(v.x); o.y = f2bf(v.y); o.z = f2bf(v.z); o.w = f2bf(v.w);
    ((ushort4*)dst)[i] = o;
}

// ---------------- token shift + time-mix (3 outputs, bf16) ----------------
__device__ __forceinline__ ushort4 mix4(const float4& a, const float4& s, const float4& m) {
    ushort4 o;
    o.x = f2bf(s.x + (a.x - s.x) * m.x);
    o.y = f2bf(s.y + (a.y - s.y) * m.y);
    o.z = f2bf(s.z + (a.z - s.z) * m.z);
    o.w = f2bf(s.w + (a.w - s.w) * m.w);
    return o;
}

__global__ __launch_bounds__(256) void mix_kernel(const float* __restrict__ x,
                                                  const float* __restrict__ tmk,
                                                  const float* __restrict__ tmv,
                                                  const float* __restrict__ tmr,
                                                  unsigned short* __restrict__ ak,
                                                  unsigned short* __restrict__ av,
                                                  unsigned short* __restrict__ ar) {
    int i = blockIdx.x * 256 + threadIdx.x;           // over Mn*Cn/4 float4s
    int c4 = i & 255;                                  // Cn/4 = 256
    int t  = (i >> 8) & (Tn - 1);
    float4 xc = ((const float4*)x)[i];
    float4 xs = make_float4(0.f, 0.f, 0.f, 0.f);
    if (t > 0) xs = ((const float4*)x)[i - 256];
    float4 mk = ((const float4*)tmk)[c4];
    float4 mv = ((const float4*)tmv)[c4];
    float4 mr = ((const float4*)tmr)[c4];
    ((ushort4*)ak)[i] = mix4(xc, xs, mk);
    ((ushort4*)av)[i] = mix4(xc, xs, mv);
    ((ushort4*)ar)[i] = mix4(xc, xs, mr);
}

// ---------------- bf16 NT GEMM: C[m,n] = sum_k A[m,k]*B[n,k] ----------------
#define BK 32

template <int FOUT>   // 0: bf16 out, 1: fp32 out
__global__ __launch_bounds__(256) void gemm_bt(const unsigned short* __restrict__ A,
                                               const unsigned short* __restrict__ Bw,
                                               unsigned short* __restrict__ Cb,
                                               float* __restrict__ Cf) {
    __shared__ unsigned short lA[128 * BK];
    __shared__ unsigned short lB[128 * BK];
    const int tid  = threadIdx.x;
    const int lane = tid & 63;
    const int wid  = tid >> 6;
    const int wr   = wid >> 1;          // wave row (0..1)
    const int wc   = wid & 1;           // wave col (0..1)
    const int bm   = blockIdx.x * 128;
    const int bn   = blockIdx.y * 128;

    const int srow = lane >> 2;         // 0..15
    const int scol = (lane & 3) * 8;    // 0,8,16,24
    const int lr   = lane & 15;
    const int lk   = (lane >> 4) * 8;

    f32x4 acc[4][4] = {};

    for (int k0 = 0; k0 < 1024; k0 += BK) {
#pragma unroll
        for (int i = 0; i < 2; ++i) {
            int r = wid * 32 + i * 16;
            const unsigned short* ga = A  + (size_t)(bm + r + srow) * 1024 + k0 + scol;
            const unsigned short* gb = Bw + (size_t)(bn + r + srow) * 1024 + k0 + scol;
            __builtin_amdgcn_global_load_lds((gas_void*)ga, (las_void*)&lA[r * BK], 16, 0, 0);
            __builtin_amdgcn_global_load_lds((gas_void*)gb, (las_void*)&lB[r * BK], 16, 0, 0);
        }
        __syncthreads();

        short8 af[4], bfv[4];
#pragma unroll
        for (int m = 0; m < 4; ++m)
            af[m] = *(const short8*)&lA[(wr * 64 + m * 16 + lr) * BK + lk];
#pragma unroll
        for (int n = 0; n < 4; ++n)
            bfv[n] = *(const short8*)&lB[(wc * 64 + n * 16 + lr) * BK + lk];
#pragma unroll
        for (int m = 0; m < 4; ++m)
#pragma unroll
            for (int n = 0; n < 4; ++n)
                acc[m][n] = __builtin_amdgcn_mfma_f32_16x16x32_bf16(af[m], bfv[n], acc[m][n], 0, 0, 0);
        __syncthreads();
    }

    const int crow0 = bm + wr * 64 + (lane >> 4) * 4;
    const int ccol0 = bn + wc * 64 + (lane & 15);
#pragma unroll
    for (int m = 0; m < 4; ++m) {
#pragma unroll
        for (int n = 0; n < 4; ++n) {
            int col = ccol0 + n * 16;
#pragma unroll
            for (int j = 0; j < 4; ++j) {
                size_t idx = (size_t)(crow0 + m * 16 + j) * 1024 + col;
                float v = acc[m][n][j];
                if (FOUT) Cf[idx] = v;
                else      Cb[idx] = f2bf(v);
            }
        }
    }
}

// ---------------- WKV pass1: per-chunk local contributions ----------------
__global__ __launch_bounds__(256) void wkv_pass1(const unsigned short* __restrict__ K,
                                                 const unsigned short* __restrict__ V,
                                                 const float* __restrict__ Wd,
                                                 float* __restrict__ caa,
                                                 float* __restrict__ cbb,
                                                 float* __restrict__ cpp) {
    int c = blockIdx.x * 256 + threadIdx.x;   // 0..1023
    int j = blockIdx.y;                        // chunk 0..NCH-1
    int b = blockIdx.z;                        // 0..7
    float w = -__expf(Wd[c]);
    float aa = 0.f, bb = 0.f, pp = -1e38f;
    size_t base = ((size_t)(b * Tn + j * LCH)) * Cn + c;
#pragma unroll 4
    for (int t = 0; t < LCH; ++t) {
        size_t idx = base + (size_t)t * Cn;
        float kt = bf2f(K[idx]);
        float vt = bf2f(V[idx]);
        float ww2 = pp + w;
        float p2  = fmaxf(ww2, kt);
        float e1  = __expf(ww2 - p2);
        float e2  = __expf(kt - p2);
        aa = e1 * aa + e2 * vt;
        bb = e1 * bb + e2;
        pp = p2;
    }
    size_t o = ((size_t)b * NCH + j) * Cn + c;
    caa[o] = aa; cbb[o] = bb; cpp[o] = pp;
}

// ---------------- WKV pass2: scan over chunks (cheap, sequential) ----------
__global__ __launch_bounds__(256) void wkv_pass2(const float* __restrict__ Wd,
                                                 const float* __restrict__ caa,
                                                 const float* __restrict__ cbb,
                                                 const float* __restrict__ cpp,
                                                 float* __restrict__ saa,
                                                 float* __restrict__ sbb,
                                                 float* __restrict__ spp) {
    int c = blockIdx.x * 256 + threadIdx.x;
    int b = blockIdx.y;
    float Lw = -__expf(Wd[c]) * (float)LCH;
    float aa = 0.f, bb = 0.f, pp = -1e38f;
    for (int j = 0; j < NCH; ++j) {
        size_t o = ((size_t)b * NCH + j) * Cn + c;
        saa[o] = aa; sbb[o] = bb; spp[o] = pp;   // incoming state for chunk j
        float qa = caa[o], qb = cbb[o], qp = cpp[o];
        float ppd = pp + Lw;
        float p  = fmaxf(ppd, qp);
        float e1 = __expf(ppd - p);
        float e2 = __expf(qp - p);
        aa = e1 * aa + e2 * qa;
        bb = e1 * bb + e2 * qb;
        pp = p;
    }
}

// ---------------- WKV pass3: replay chunk with true state + gating --------
__global__ __launch_bounds__(256) void wkv_pass3(const unsigned short* __restrict__ K,
                                                 const unsigned short* __restrict__ V,
                                                 const unsigned short* __restrict__ Rb,
                                                 const float* __restrict__ Wd,
                                                 const float* __restrict__ Ud,
                                                 const float* __restrict__ saa,
                                                 const float* __restrict__ sbb,
                                                 const float* __restrict__ spp,
                                                 unsigned short* __restrict__ rwkv,
                                                 float* __restrict__ hidden) {
    int c = blockIdx.x * 256 + threadIdx.x;
    int j = blockIdx.y;
    int b = blockIdx.z;
    float w = -__expf(Wd[c]);
    float u = Ud[c];
    size_t o = ((size_t)b * NCH + j) * Cn + c;
    float aa = saa[o], bb = sbb[o], pp = spp[o];
    size_t base = ((size_t)(b * Tn + j * LCH)) * Cn + c;
    float y = 0.f;
#pragma unroll 4
    for (int t = 0; t < LCH; ++t) {
        size_t idx = base + (size_t)t * Cn;
        float kt = bf2f(K[idx]);
        float vt = bf2f(V[idx]);
        float rt = bf2f(Rb[idx]);
        float ww = u + kt;
        float p  = fmaxf(pp, ww);
        float e1 = __expf(pp - p);
        float e2 = __expf(ww - p);
        y = __fdividef(e1 * aa + e2 * vt, e1 * bb + e2);
        float sr = __fdividef(1.f, 1.f + __expf(-rt));
        rwkv[idx] = f2bf(sr * y);
        float ww2 = pp + w;
        float p2  = fmaxf(ww2, kt);
        float e1b = __expf(ww2 - p2);
        float e2b = __expf(kt - p2);
        aa = e1b * aa + e2b * vt;
        bb = e1b * bb + e2b;
        pp = p2;
    }
    if (j == NCH - 1) hidden[b * Cn + c] = y;
}

// ---------------- launcher ----------------
extern "C" void kernel_launch(void* const* d_in, const int* in_sizes, int n_in,
                              void* d_out, int out_size, void* d_ws, size_t ws_size,
                              hipStream_t stream) {
    const float* x   = (const float*)d_in[0];
    const float* Wd  = (const float*)d_in[1];
    const float* Ud  = (const float*)d_in[2];
    const float* tmk = (const float*)d_in[3];
    const float* tmv = (const float*)d_in[4];
    const float* tmr = (const float*)d_in[5];
    const float* Wk  = (const float*)d_in[6];
    const float* Wv  = (const float*)d_in[7];
    const float* Wr  = (const float*)d_in[8];
    const float* Wo  = (const float*)d_in[9];

    float* out    = (float*)d_out;
    float* hidden = out + (size_t)Mn * Cn;

    const size_t MK = (size_t)Mn * Cn;   // 16,777,216 elements
    const size_t CC = (size_t)Cn * Cn;   // 1,048,576 elements
    unsigned short* ak  = (unsigned short*)d_ws;   // [0, MK)
    unsigned short* av  = ak + MK;
    unsigned short* ar  = av + MK;
    unsigned short* Kb  = ar + MK;
    unsigned short* Wkb = Kb + MK;
    unsigned short* Wvb = Wkb + CC;
    unsigned short* Wrb = Wvb + CC;
    unsigned short* Wob = Wrb + CC;
    // overlays (safe by dataflow order):
    unsigned short* Vb = ak;   // ak dead after GEMM-K
    unsigned short* Rb = av;   // av dead after GEMM-V
    unsigned short* rw = ar;   // ar dead after GEMM-R
    // chunk-state arrays overlay Wkb/Wvb/Wrb (dead after their GEMMs):
    // 6 arrays x Bn*NCH*Cn floats = 6 MB = exactly 3*CC*2 bytes
    const size_t SB = (size_t)Bn * NCH * Cn;       // 262,144
    float* caa = (float*)Wkb;
    float* cbb = caa + SB;
    float* cpp = cbb + SB;
    float* saa = cpp + SB;
    float* sbb = saa + SB;
    float* spp = sbb + SB;

    cvt_kernel<<<dim3(CC / 1024), 256, 0, stream>>>(Wk, Wkb);
    cvt_kernel<<<dim3(CC / 1024), 256, 0, stream>>>(Wv, Wvb);
    cvt_kernel<<<dim3(CC / 1024), 256, 0, stream>>>(Wr, Wrb);
    cvt_kernel<<<dim3(CC / 1024), 256, 0, stream>>>(Wo, Wob);

    mix_kernel<<<dim3(MK / 1024), 256, 0, stream>>>(x, tmk, tmv, tmr, ak, av, ar);

    dim3 gg(Mn / 128, Cn / 128);   // (128, 8)
    gemm_bt<0><<<gg, 256, 0, stream>>>(ak, Wkb, Kb, nullptr);
    gemm_bt<0><<<gg, 256, 0, stream>>>(av, Wvb, Vb, nullptr);
    gemm_bt<0><<<gg, 256, 0, stream>>>(ar, Wrb, Rb, nullptr);

    dim3 gw(Cn / 256, NCH, Bn);    // (4, 32, 8)
    wkv_pass1<<<gw, 256, 0, stream>>>(Kb, Vb, Wd, caa, cbb, cpp);
    wkv_pass2<<<dim3(Cn / 256, Bn), 256, 0, stream>>>(Wd, caa, cbb, cpp, saa, sbb, spp);
    wkv_pass3<<<gw, 256, 0, stream>>>(Kb, Vb, Rb, Wd, Ud, saa, sbb, spp, rw, hidden);

    gemm_bt<1><<<gg, 256, 0, stream>>>(rw, Wob, nullptr, out);
}

// Round 5
// 383.875 us; speedup vs baseline: 3.0583x; 1.0639x over previous
//
#include <hip/hip_runtime.h>

#define Bn 8
#define Tn 2048
#define Cn 1024
#define Mn (Bn * Tn)   // 16384 rows
#define LCH 64
#define NCH (Tn / LCH) // 32 chunks

typedef __attribute__((ext_vector_type(8))) short short8;
typedef __attribute__((ext_vector_type(4))) float f32x4;

typedef const __attribute__((address_space(1))) void gas_void;
typedef __attribute__((address_space(3))) void las_void;

__device__ __forceinline__ unsigned short f2bf(float f) {
    unsigned int u = __float_as_uint(f);
    u += 0x7FFFu + ((u >> 16) & 1u);   // round-to-nearest-even
    return (unsigned short)(u >> 16);
}
__device__ __forceinline__ float bf2f(unsigned short h) {
    return __uint_as_float(((unsigned int)h) << 16);
}

// ---------------- weight fp32 -> bf16 convert ----------------
__global__ __launch_bounds__(256) void cvt_kernel(const float* __restrict__ src,
                                                  unsigned short* __restrict__ dst) {
    int i = blockIdx.x * 256 + threadIdx.x;           // over C*C/4 float4s
    float4 v = ((const float4*)src)[i];
    ushort4 o;
    o.x = f2bf(v.x); o.y = f2bf(v.y); o.z = f2bf(v.z); o.w = f2bf(v.w);
    ((ushort4*)dst)[i] = o;
}

// ---------------- token shift + time-mix (3 outputs, bf16) ----------------
__device__ __forceinline__ ushort4 mix4(const float4& a, const float4& s, const float4& m) {
    ushort4 o;
    o.x = f2bf(s.x + (a.x - s.x) * m.x);
    o.y = f2bf(s.y + (a.y - s.y) * m.y);
    o.z = f2bf(s.z + (a.z - s.z) * m.z);
    o.w = f2bf(s.w + (a.w - s.w) * m.w);
    return o;
}

__global__ __launch_bounds__(256) void mix_kernel(const float* __restrict__ x,
                                                  const float* __restrict__ tmk,
                                                  const float* __restrict__ tmv,
                                                  const float* __restrict__ tmr,
                                                  unsigned short* __restrict__ ak,
                                                  unsigned short* __restrict__ av,
                                                  unsigned short* __restrict__ ar) {
    int i = blockIdx.x * 256 + threadIdx.x;           // over Mn*Cn/4 float4s
    int c4 = i & 255;                                  // Cn/4 = 256
    int t  = (i >> 8) & (Tn - 1);
    float4 xc = ((const float4*)x)[i];
    float4 xs = make_float4(0.f, 0.f, 0.f, 0.f);
    if (t > 0) xs = ((const float4*)x)[i - 256];
    float4 mk = ((const float4*)tmk)[c4];
    float4 mv = ((const float4*)tmv)[c4];
    float4 mr = ((const float4*)tmr)[c4];
    ((ushort4*)ak)[i] = mix4(xc, xs, mk);
    ((ushort4*)av)[i] = mix4(xc, xs, mv);
    ((ushort4*)ar)[i] = mix4(xc, xs, mr);
}

// ======================= bf16 NT GEMM, phase-split pipeline ================
// C[m,n] = sum_k A[m,k]*B[n,k].  M=16384, N=1024, K=1024.
// BM=256, BN=128, BK=64. 8 waves (2Mx4N), per-wave output 128x32.
// 3 LDS buffers (whole K-tile each: A 32KB + B 16KB = 48KB; 144KB total).
// Stage tile t+2 while computing tile t -> per-tile sync = vmcnt(6), never 0.
// LDS XOR swizzle: phys_byte = logical ^ ((row&7)<<4), applied by
// pre-swizzling the per-lane GLOBAL source (linear gload_lds dest) and
// XOR-ing the ds_read slot. Conflict-free: 2 lanes/bank per 16-lane group.

#define NT 16            // K / 64
#define BUFB 49152       // bytes per buffer (A 32768 + B 16384)

#define PHASE_BAR() asm volatile("s_barrier" ::: "memory")
#define WAITV6()    asm volatile("s_waitcnt vmcnt(6)" ::: "memory")
#define WAITV0()    asm volatile("s_waitcnt vmcnt(0)" ::: "memory")

// stage 128 rows x 64 cols (bf16) from gbase (points at row0,k0; row stride
// 1024 shorts) into ldsbase; 2 gload_lds per wave.
__device__ __forceinline__ void stage_rows(const unsigned short* gbase,
                                           char* ldsbase, int lane, int wid) {
    int rowg = wid * 16 + (lane >> 3);            // wave rows: wid*16 .. +15
    int slot = (lane & 7) ^ (lane >> 3);          // pre-swizzled source slot
    const unsigned short* s0 = gbase + (size_t)rowg * 1024 + slot * 8;
    const unsigned short* s1 = gbase + (size_t)(rowg + 8) * 1024 + slot * 8;
    char* d0 = ldsbase + (wid * 16) * 128;        // wave-uniform dest
    char* d1 = ldsbase + (wid * 16 + 8) * 128;
    __builtin_amdgcn_global_load_lds((gas_void*)s0, (las_void*)d0, 16, 0, 0);
    __builtin_amdgcn_global_load_lds((gas_void*)s1, (las_void*)d1, 16, 0, 0);
}

template <int FOUT>   // 0: bf16 out, 1: fp32 out
__global__ __launch_bounds__(512, 2) void gemm_bt(const unsigned short* __restrict__ A,
                                                  const unsigned short* __restrict__ Bw,
                                                  unsigned short* __restrict__ Cb,
                                                  float* __restrict__ Cf) {
    __shared__ char lds[3 * BUFB];
    const int tid  = threadIdx.x;
    const int lane = tid & 63;
    const int wid  = tid >> 6;          // 0..7
    const int wr   = wid >> 2;          // 0..1 (M half)
    const int wc   = wid & 3;           // 0..3 (N quarter)
    const int bm   = blockIdx.x * 256;
    const int bn   = blockIdx.y * 128;

    const int lr = lane & 15;
    const int q  = lane >> 4;           // 0..3
    const int s7 = lr & 7;              // swizzle row bits for reads

    f32x4 acc[8][2] = {};

    // ---- prologue: stage tiles 0 and 1 ----
    stage_rows(A  + (size_t)bm * 1024,                 lds,                 lane, wid);
    stage_rows(A  + (size_t)(bm + 128) * 1024,         lds + 16384,         lane, wid);
    stage_rows(Bw + (size_t)bn * 1024,                 lds + 32768,         lane, wid);
    stage_rows(A  + (size_t)bm * 1024 + 64,            lds + BUFB,          lane, wid);
    stage_rows(A  + (size_t)(bm + 128) * 1024 + 64,    lds + BUFB + 16384,  lane, wid);
    stage_rows(Bw + (size_t)bn * 1024 + 64,            lds + BUFB + 32768,  lane, wid);
    WAITV6();            // tile 0 landed (tile 1's 6 loads may remain)
    PHASE_BAR();

    int cur = 0, nxt2 = 2;
#pragma unroll 1
    for (int t = 0; t < NT; ++t) {
        char* Ab = lds + cur * BUFB;
        char* Bb = Ab + 32768;
        const bool st = (t + 2) < NT;
        char* An = lds + nxt2 * BUFB;
        const unsigned short* gA = A  + (size_t)bm * 1024 + (t + 2) * 64;
        const unsigned short* gB = Bw + (size_t)bn * 1024 + (t + 2) * 64;

        short8 af[8], bf0, bf1;
        // ---- P0: stage A(t+2) rows 0-127; read A kk=0 + B(0,0); 8 MFMA ----
        if (st) stage_rows(gA, An, lane, wid);
#pragma unroll
        for (int mi = 0; mi < 8; ++mi)
            af[mi] = *(const short8*)(Ab + (wr * 128 + mi * 16 + lr) * 128 + ((q ^ s7) << 4));
        bf0 = *(const short8*)(Bb + (wc * 32 + lr) * 128 + ((q ^ s7) << 4));
        __builtin_amdgcn_s_setprio(1);
#pragma unroll
        for (int mi = 0; mi < 8; ++mi)
            acc[mi][0] = __builtin_amdgcn_mfma_f32_16x16x32_bf16(af[mi], bf0, acc[mi][0], 0, 0, 0);
        __builtin_amdgcn_s_setprio(0);
        PHASE_BAR();

        // ---- P1: stage A(t+2) rows 128-255; read B(1,0); 8 MFMA ----
        if (st) stage_rows(gA + (size_t)128 * 1024, An + 16384, lane, wid);
        bf1 = *(const short8*)(Bb + (wc * 32 + 16 + lr) * 128 + ((q ^ s7) << 4));
        __builtin_amdgcn_s_setprio(1);
#pragma unroll
        for (int mi = 0; mi < 8; ++mi)
            acc[mi][1] = __builtin_amdgcn_mfma_f32_16x16x32_bf16(af[mi], bf1, acc[mi][1], 0, 0, 0);
        __builtin_amdgcn_s_setprio(0);
        PHASE_BAR();

        // ---- P2: stage B(t+2); read A kk=1 + B(0,1); 8 MFMA ----
        if (st) stage_rows(gB, An + 32768, lane, wid);
#pragma unroll
        for (int mi = 0; mi < 8; ++mi)
            af[mi] = *(const short8*)(Ab + (wr * 128 + mi * 16 + lr) * 128 + (((q | 4) ^ s7) << 4));
        bf0 = *(const short8*)(Bb + (wc * 32 + lr) * 128 + (((q | 4) ^ s7) << 4));
        __builtin_amdgcn_s_setprio(1);
#pragma unroll
        for (int mi = 0; mi < 8; ++mi)
            acc[mi][0] = __builtin_amdgcn_mfma_f32_16x16x32_bf16(af[mi], bf0, acc[mi][0], 0, 0, 0);
        __builtin_amdgcn_s_setprio(0);
        PHASE_BAR();

        // ---- P3: read B(1,1); 8 MFMA; counted sync for next tile ----
        bf1 = *(const short8*)(Bb + (wc * 32 + 16 + lr) * 128 + (((q | 4) ^ s7) << 4));
        __builtin_amdgcn_s_setprio(1);
#pragma unroll
        for (int mi = 0; mi < 8; ++mi)
            acc[mi][1] = __builtin_amdgcn_mfma_f32_16x16x32_bf16(af[mi], bf1, acc[mi][1], 0, 0, 0);
        __builtin_amdgcn_s_setprio(0);
        if (t <= NT - 3) { WAITV6(); } else { WAITV0(); }
        PHASE_BAR();

        cur  = (cur  == 2) ? 0 : cur + 1;
        nxt2 = (nxt2 == 2) ? 0 : nxt2 + 1;
    }

    // ---- epilogue: C/D layout col=lane&15, row=(lane>>4)*4+reg ----
    const int crow0 = bm + wr * 128 + q * 4;
    const int ccol0 = bn + wc * 32 + lr;
#pragma unroll
    for (int mi = 0; mi < 8; ++mi) {
#pragma unroll
        for (int ni = 0; ni < 2; ++ni) {
            int col = ccol0 + ni * 16;
#pragma unroll
            for (int j = 0; j < 4; ++j) {
                size_t idx = (size_t)(crow0 + mi * 16 + j) * 1024 + col;
                float v = acc[mi][ni][j];
                if (FOUT) Cf[idx] = v;
                else      Cb[idx] = f2bf(v);
            }
        }
    }
}

// ---------------- WKV pass1: per-chunk local contributions ----------------
__global__ __launch_bounds__(256) void wkv_pass1(const unsigned short* __restrict__ K,
                                                 const unsigned short* __restrict__ V,
                                                 const float* __restrict__ Wd,
                                                 float* __restrict__ caa,
                                                 float* __restrict__ cbb,
                                                 float* __restrict__ cpp) {
    int c = blockIdx.x * 256 + threadIdx.x;   // 0..1023
    int j = blockIdx.y;                        // chunk 0..NCH-1
    int b = blockIdx.z;                        // 0..7
    float w = -__expf(Wd[c]);
    float aa = 0.f, bb = 0.f, pp = -1e38f;
    size_t base = ((size_t)(b * Tn + j * LCH)) * Cn + c;
#pragma unroll 4
    for (int t = 0; t < LCH; ++t) {
        size_t idx = base + (size_t)t * Cn;
        float kt = bf2f(K[idx]);
        float vt = bf2f(V[idx]);
        float ww2 = pp + w;
        float p2  = fmaxf(ww2, kt);
        float e1  = __expf(ww2 - p2);
        float e2  = __expf(kt - p2);
        aa = e1 * aa + e2 * vt;
        bb = e1 * bb + e2;
        pp = p2;
    }
    size_t o = ((size_t)b * NCH + j) * Cn + c;
    caa[o] = aa; cbb[o] = bb; cpp[o] = pp;
}

// ---------------- WKV pass2: scan over chunks (cheap, sequential) ----------
__global__ __launch_bounds__(256) void wkv_pass2(const float* __restrict__ Wd,
                                                 const float* __restrict__ caa,
                                                 const float* __restrict__ cbb,
                                                 const float* __restrict__ cpp,
                                                 float* __restrict__ saa,
                                                 float* __restrict__ sbb,
                                                 float* __restrict__ spp) {
    int c = blockIdx.x * 256 + threadIdx.x;
    int b = blockIdx.y;
    float Lw = -__expf(Wd[c]) * (float)LCH;
    float aa = 0.f, bb = 0.f, pp = -1e38f;
    for (int j = 0; j < NCH; ++j) {
        size_t o = ((size_t)b * NCH + j) * Cn + c;
        saa[o] = aa; sbb[o] = bb; spp[o] = pp;   // incoming state for chunk j
        float qa = caa[o], qb = cbb[o], qp = cpp[o];
        float ppd = pp + Lw;
        float p  = fmaxf(ppd, qp);
        float e1 = __expf(ppd - p);
        float e2 = __expf(qp - p);
        aa = e1 * aa + e2 * qa;
        bb = e1 * bb + e2 * qb;
        pp = p;
    }
}

// ---------------- WKV pass3: replay chunk with true state + gating --------
__global__ __launch_bounds__(256) void wkv_pass3(const unsigned short* __restrict__ K,
                                                 const unsigned short* __restrict__ V,
                                                 const unsigned short* __restrict__ Rb,
                                                 const float* __restrict__ Wd,
                                                 const float* __restrict__ Ud,
                                                 const float* __restrict__ saa,
                                                 const float* __restrict__ sbb,
                                                 const float* __restrict__ spp,
                                                 unsigned short* __restrict__ rwkv,
                                                 float* __restrict__ hidden) {
    int c = blockIdx.x * 256 + threadIdx.x;
    int j = blockIdx.y;
    int b = blockIdx.z;
    float w = -__expf(Wd[c]);
    float u = Ud[c];
    size_t o = ((size_t)b * NCH + j) * Cn + c;
    float aa = saa[o], bb = sbb[o], pp = spp[o];
    size_t base = ((size_t)(b * Tn + j * LCH)) * Cn + c;
    float y = 0.f;
#pragma unroll 4
    for (int t = 0; t < LCH; ++t) {
        size_t idx = base + (size_t)t * Cn;
        float kt = bf2f(K[idx]);
        float vt = bf2f(V[idx]);
        float rt = bf2f(Rb[idx]);
        float ww = u + kt;
        float p  = fmaxf(pp, ww);
        float e1 = __expf(pp - p);
        float e2 = __expf(ww - p);
        y = __fdividef(e1 * aa + e2 * vt, e1 * bb + e2);
        float sr = __fdividef(1.f, 1.f + __expf(-rt));
        rwkv[idx] = f2bf(sr * y);
        float ww2 = pp + w;
        float p2  = fmaxf(ww2, kt);
        float e1b = __expf(ww2 - p2);
        float e2b = __expf(kt - p2);
        aa = e1b * aa + e2b * vt;
        bb = e1b * bb + e2b;
        pp = p2;
    }
    if (j == NCH - 1) hidden[b * Cn + c] = y;
}

// ---------------- launcher ----------------
extern "C" void kernel_launch(void* const* d_in, const int* in_sizes, int n_in,
                              void* d_out, int out_size, void* d_ws, size_t ws_size,
                              hipStream_t stream) {
    const float* x   = (const float*)d_in[0];
    const float* Wd  = (const float*)d_in[1];
    const float* Ud  = (const float*)d_in[2];
    const float* tmk = (const float*)d_in[3];
    const float* tmv = (const float*)d_in[4];
    const float* tmr = (const float*)d_in[5];
    const float* Wk  = (const float*)d_in[6];
    const float* Wv  = (const float*)d_in[7];
    const float* Wr  = (const float*)d_in[8];
    const float* Wo  = (const float*)d_in[9];

    float* out    = (float*)d_out;
    float* hidden = out + (size_t)Mn * Cn;

    const size_t MK = (size_t)Mn * Cn;   // 16,777,216 elements
    const size_t CC = (size_t)Cn * Cn;   // 1,048,576 elements
    unsigned short* ak  = (unsigned short*)d_ws;   // [0, MK)
    unsigned short* av  = ak + MK;
    unsigned short* ar  = av + MK;
    unsigned short* Kb  = ar + MK;
    unsigned short* Wkb = Kb + MK;
    unsigned short* Wvb = Wkb + CC;
    unsigned short* Wrb = Wvb + CC;
    unsigned short* Wob = Wrb + CC;
    // overlays (safe by dataflow order):
    unsigned short* Vb = ak;   // ak dead after GEMM-K
    unsigned short* Rb = av;   // av dead after GEMM-V
    unsigned short* rw = ar;   // ar dead after GEMM-R
    // chunk-state arrays overlay Wkb/Wvb/Wrb (dead after their GEMMs):
    const size_t SB = (size_t)Bn * NCH * Cn;       // 262,144
    float* caa = (float*)Wkb;
    float* cbb = caa + SB;
    float* cpp = cbb + SB;
    float* saa = cpp + SB;
    float* sbb = saa + SB;
    float* spp = sbb + SB;

    cvt_kernel<<<dim3(CC / 1024), 256, 0, stream>>>(Wk, Wkb);
    cvt_kernel<<<dim3(CC / 1024), 256, 0, stream>>>(Wv, Wvb);
    cvt_kernel<<<dim3(CC / 1024), 256, 0, stream>>>(Wr, Wrb);
    cvt_kernel<<<dim3(CC / 1024), 256, 0, stream>>>(Wo, Wob);

    mix_kernel<<<dim3(MK / 1024), 256, 0, stream>>>(x, tmk, tmv, tmr, ak, av, ar);

    dim3 gg(Mn / 256, Cn / 128);   // (64, 8)
    gemm_bt<0><<<gg, 512, 0, stream>>>(ak, Wkb, Kb, nullptr);
    gemm_bt<0><<<gg, 512, 0, stream>>>(av, Wvb, Vb, nullptr);
    gemm_bt<0><<<gg, 512, 0, stream>>>(ar, Wrb, Rb, nullptr);

    dim3 gw(Cn / 256, NCH, Bn);    // (4, 32, 8)
    wkv_pass1<<<gw, 256, 0, stream>>>(Kb, Vb, Wd, caa, cbb, cpp);
    wkv_pass2<<<dim3(Cn / 256, Bn), 256, 0, stream>>>(Wd, caa, cbb, cpp, saa, sbb, spp);
    wkv_pass3<<<gw, 256, 0, stream>>>(Kb, Vb, Rb, Wd, Ud, saa, sbb, spp, rw, hidden);

    gemm_bt<1><<<gg, 512, 0, stream>>>(rw, Wob, nullptr, out);
}

// Round 6
// 362.316 us; speedup vs baseline: 3.2403x; 1.0595x over previous
//
#include <hip/hip_runtime.h>

#define Bn 8
#define Tn 2048
#define Cn 1024
#define Mn (Bn * Tn)   // 16384 rows
#define LCH 64
#define NCH (Tn / LCH) // 32 chunks

typedef __attribute__((ext_vector_type(8))) short short8;
typedef __attribute__((ext_vector_type(4))) float f32x4;

typedef const __attribute__((address_space(1))) void gas_void;
typedef __attribute__((address_space(3))) void las_void;

__device__ __forceinline__ unsigned short f2bf(float f) {
    unsigned int u = __float_as_uint(f);
    u += 0x7FFFu + ((u >> 16) & 1u);   // round-to-nearest-even
    return (unsigned short)(u >> 16);
}
__device__ __forceinline__ float bf2f(unsigned short h) {
    return __uint_as_float(((unsigned int)h) << 16);
}

// ---------------- weight fp32 -> bf16 convert ----------------
__global__ __launch_bounds__(256) void cvt_kernel(const float* __restrict__ src,
                                                  unsigned short* __restrict__ dst) {
    int i = blockIdx.x * 256 + threadIdx.x;           // over C*C/4 float4s
    float4 v = ((const float4*)src)[i];
    ushort4 o;
    o.x = f2bf(v.x); o.y = f2bf(v.y); o.z = f2bf(v.z); o.w = f2bf(v.w);
    ((ushort4*)dst)[i] = o;
}

// ---------------- token shift + time-mix (3 outputs, bf16) ----------------
__device__ __forceinline__ ushort4 mix4(const float4& a, const float4& s, const float4& m) {
    ushort4 o;
    o.x = f2bf(s.x + (a.x - s.x) * m.x);
    o.y = f2bf(s.y + (a.y - s.y) * m.y);
    o.z = f2bf(s.z + (a.z - s.z) * m.z);
    o.w = f2bf(s.w + (a.w - s.w) * m.w);
    return o;
}

__global__ __launch_bounds__(256) void mix_kernel(const float* __restrict__ x,
                                                  const float* __restrict__ tmk,
                                                  const float* __restrict__ tmv,
                                                  const float* __restrict__ tmr,
                                                  unsigned short* __restrict__ ak,
                                                  unsigned short* __restrict__ av,
                                                  unsigned short* __restrict__ ar) {
    int i = blockIdx.x * 256 + threadIdx.x;           // over Mn*Cn/4 float4s
    int c4 = i & 255;                                  // Cn/4 = 256
    int t  = (i >> 8) & (Tn - 1);
    float4 xc = ((const float4*)x)[i];
    float4 xs = make_float4(0.f, 0.f, 0.f, 0.f);
    if (t > 0) xs = ((const float4*)x)[i - 256];
    float4 mk = ((const float4*)tmk)[c4];
    float4 mv = ((const float4*)tmv)[c4];
    float4 mr = ((const float4*)tmr)[c4];
    ((ushort4*)ak)[i] = mix4(xc, xs, mk);
    ((ushort4*)av)[i] = mix4(xc, xs, mv);
    ((ushort4*)ar)[i] = mix4(xc, xs, mr);
}

// ======================= bf16 NT GEMM, 256x256 read-ahead pipeline =========
// C[m,n] = sum_k A[m,k]*B[n,k].  M=16384, N=1024, K=1024.
// BM=BN=256, BK=32. 8 waves (2M x 4N), wave-tile 128x64 (acc 8x4).
// 4 LDS buffers x 32KB (A 16KB + B 16KB) = 128KB. Stage 3 tiles ahead;
// per-tile sync = vmcnt(4) (4 gloads/wave/tile) -> bufs t+1,t+2 proven at
// each tile entry, enabling register read-ahead from buf t+1.
// Swizzle (64B rows, 4 slots of 16B): phys_slot = q ^ ((row>>1)&3);
// applied via pre-swizzled GLOBAL source (linear gload_lds dest) and the
// same XOR on ds_read -> each bank-quad hit exactly 2x (conflict-free).

#define BKg  32
#define NTg  32                    // K / BKg
#define ABYT (256 * BKg * 2)       // 16384 bytes (A region per buffer)
#define BUFBY (2 * ABYT)           // 32768 bytes per buffer

#define PHASE_BAR() asm volatile("s_barrier" ::: "memory")
#define WAITV4()    asm volatile("s_waitcnt vmcnt(4)" ::: "memory")
#define WAITV0()    asm volatile("s_waitcnt vmcnt(0)" ::: "memory")

// stage one 16-row x 32-col group (1KB): gbase -> row0,k0 of the group;
// LDS dest linear (row*64 bytes); source column slot pre-swizzled.
__device__ __forceinline__ void stage16(const unsigned short* gbase,
                                        char* ldsdst, int lane) {
    int r = lane >> 2;
    int g = (lane & 3) ^ ((lane >> 3) & 3);   // inverse swizzle on source
    const unsigned short* src = gbase + (size_t)r * 1024 + g * 8;
    __builtin_amdgcn_global_load_lds((gas_void*)src, (las_void*)ldsdst, 16, 0, 0);
}

__device__ __forceinline__ void gemm_body(int t,
    const unsigned short* __restrict__ A, const unsigned short* __restrict__ Bw,
    char* lds, int bm, int bn, int lane, int wid, int wr, int wc, int lr, int rsw,
    short8* afc, short8* bfc, short8* afn, short8* bfn, f32x4 acc[8][4]) {
    char* Ab = lds + (size_t)(t & 3) * BUFBY;          // current tile
    char* Bb = Ab + ABYT;
    char* An = lds + (size_t)((t + 3) & 3) * BUFBY;    // stage target
    char* Bs = An + ABYT;
    char* A1 = lds + (size_t)((t + 1) & 3) * BUFBY;    // read-ahead source
    char* B1 = A1 + ABYT;
    const bool st = (t + 3) < NTg;
    const bool ra = (t + 1) < NTg;
    const int k0 = (t + 3) * BKg;

    // ---- Ph0: stage A(t+3) h0; read afc[4..7] (current buf, used Ph2); MFMA m0,m1
    if (st) stage16(A + (size_t)(bm + wid * 16) * 1024 + k0, An + wid * 16 * 64, lane);
#pragma unroll
    for (int mi = 4; mi < 8; ++mi)
        afc[mi] = *(const short8*)(Ab + (wr * 128 + mi * 16 + lr) * 64 + rsw);
    __builtin_amdgcn_s_setprio(1);
#pragma unroll
    for (int mi = 0; mi < 2; ++mi)
#pragma unroll
        for (int ni = 0; ni < 4; ++ni)
            acc[mi][ni] = __builtin_amdgcn_mfma_f32_16x16x32_bf16(afc[mi], bfc[ni], acc[mi][ni], 0, 0, 0);
    __builtin_amdgcn_s_setprio(0);
    PHASE_BAR();

    // ---- Ph1: stage A(t+3) h1; read bfn[0..3] (buf t+1); MFMA m2,m3
    if (st) stage16(A + (size_t)(bm + 128 + wid * 16) * 1024 + k0, An + (128 + wid * 16) * 64, lane);
    if (ra) {
#pragma unroll
        for (int ni = 0; ni < 4; ++ni)
            bfn[ni] = *(const short8*)(B1 + (wc * 64 + ni * 16 + lr) * 64 + rsw);
    }
    __builtin_amdgcn_s_setprio(1);
#pragma unroll
    for (int mi = 2; mi < 4; ++mi)
#pragma unroll
        for (int ni = 0; ni < 4; ++ni)
            acc[mi][ni] = __builtin_amdgcn_mfma_f32_16x16x32_bf16(afc[mi], bfc[ni], acc[mi][ni], 0, 0, 0);
    __builtin_amdgcn_s_setprio(0);
    PHASE_BAR();

    // ---- Ph2: stage B(t+3) h0; read afn[0..3] (buf t+1); MFMA m4,m5
    if (st) stage16(Bw + (size_t)(bn + wid * 16) * 1024 + k0, Bs + wid * 16 * 64, lane);
    if (ra) {
#pragma unroll
        for (int mi = 0; mi < 4; ++mi)
            afn[mi] = *(const short8*)(A1 + (wr * 128 + mi * 16 + lr) * 64 + rsw);
    }
    __builtin_amdgcn_s_setprio(1);
#pragma unroll
    for (int mi = 4; mi < 6; ++mi)
#pragma unroll
        for (int ni = 0; ni < 4; ++ni)
            acc[mi][ni] = __builtin_amdgcn_mfma_f32_16x16x32_bf16(afc[mi], bfc[ni], acc[mi][ni], 0, 0, 0);
    __builtin_amdgcn_s_setprio(0);
    PHASE_BAR();

    // ---- Ph3: stage B(t+3) h1; MFMA m6,m7; counted sync
    if (st) stage16(Bw + (size_t)(bn + 128 + wid * 16) * 1024 + k0, Bs + (128 + wid * 16) * 64, lane);
    __builtin_amdgcn_s_setprio(1);
#pragma unroll
    for (int mi = 6; mi < 8; ++mi)
#pragma unroll
        for (int ni = 0; ni < 4; ++ni)
            acc[mi][ni] = __builtin_amdgcn_mfma_f32_16x16x32_bf16(afc[mi], bfc[ni], acc[mi][ni], 0, 0, 0);
    __builtin_amdgcn_s_setprio(0);
    if (st) { WAITV4(); } else { WAITV0(); }
    PHASE_BAR();
}

template <int FOUT>   // 0: bf16 out, 1: fp32 out
__global__ __launch_bounds__(512, 2) void gemm_bt(const unsigned short* __restrict__ A,
                                                  const unsigned short* __restrict__ Bw,
                                                  unsigned short* __restrict__ Cb,
                                                  float* __restrict__ Cf) {
    __shared__ char lds[4 * BUFBY];     // 128 KB
    const int tid  = threadIdx.x;
    const int lane = tid & 63;
    const int wid  = tid >> 6;          // 0..7
    const int wr   = wid >> 2;          // 0..1 (M half)
    const int wc   = wid & 3;           // 0..3 (N quarter)
    const int bm   = blockIdx.x * 256;
    const int bn   = blockIdx.y * 256;

    const int lr  = lane & 15;
    const int rsw = (((lane >> 4) ^ ((lane >> 1) & 3)) << 4);

    f32x4 acc[8][4] = {};
    short8 afA[8], bfA[4], afB[8], bfB[4];

    // ---- prologue: stage tiles 0,1,2 (bufs 0,1,2) ----
#pragma unroll
    for (int i = 0; i < 3; ++i) {
        char* Ad = lds + (size_t)i * BUFBY;
        int k0 = i * BKg;
        stage16(A  + (size_t)(bm + wid * 16) * 1024 + k0,       Ad + wid * 16 * 64, lane);
        stage16(A  + (size_t)(bm + 128 + wid * 16) * 1024 + k0, Ad + (128 + wid * 16) * 64, lane);
        stage16(Bw + (size_t)(bn + wid * 16) * 1024 + k0,       Ad + ABYT + wid * 16 * 64, lane);
        stage16(Bw + (size_t)(bn + 128 + wid * 16) * 1024 + k0, Ad + ABYT + (128 + wid * 16) * 64, lane);
    }
    WAITV4();        // bufs 0,1 landed (buf 2's 4 loads may float)
    PHASE_BAR();

    // tile-0 fragments (first half of A, all B)
#pragma unroll
    for (int mi = 0; mi < 4; ++mi)
        afA[mi] = *(const short8*)(lds + (wr * 128 + mi * 16 + lr) * 64 + rsw);
#pragma unroll
    for (int ni = 0; ni < 4; ++ni)
        bfA[ni] = *(const short8*)(lds + ABYT + (wc * 64 + ni * 16 + lr) * 64 + rsw);

#pragma unroll 1
    for (int t = 0; t < NTg; t += 2) {
        gemm_body(t,     A, Bw, lds, bm, bn, lane, wid, wr, wc, lr, rsw, afA, bfA, afB, bfB, acc);
        gemm_body(t + 1, A, Bw, lds, bm, bn, lane, wid, wr, wc, lr, rsw, afB, bfB, afA, bfA, acc);
    }

    // ---- epilogue: C/D layout col=lane&15, row=(lane>>4)*4+reg ----
    const int crow0 = bm + wr * 128 + (lane >> 4) * 4;
    const int ccol0 = bn + wc * 64 + lr;
#pragma unroll
    for (int mi = 0; mi < 8; ++mi) {
#pragma unroll
        for (int ni = 0; ni < 4; ++ni) {
            int col = ccol0 + ni * 16;
#pragma unroll
            for (int j = 0; j < 4; ++j) {
                size_t idx = (size_t)(crow0 + mi * 16 + j) * 1024 + col;
                float v = acc[mi][ni][j];
                if (FOUT) Cf[idx] = v;
                else      Cb[idx] = f2bf(v);
            }
        }
    }
}

// ---------------- WKV pass1: per-chunk local contributions ----------------
__global__ __launch_bounds__(256) void wkv_pass1(const unsigned short* __restrict__ K,
                                                 const unsigned short* __restrict__ V,
                                                 const float* __restrict__ Wd,
                                                 float* __restrict__ caa,
                                                 float* __restrict__ cbb,
                                                 float* __restrict__ cpp) {
    int c = blockIdx.x * 256 + threadIdx.x;   // 0..1023
    int j = blockIdx.y;                        // chunk 0..NCH-1
    int b = blockIdx.z;                        // 0..7
    float w = -__expf(Wd[c]);
    float aa = 0.f, bb = 0.f, pp = -1e38f;
    size_t base = ((size_t)(b * Tn + j * LCH)) * Cn + c;
#pragma unroll 4
    for (int t = 0; t < LCH; ++t) {
        size_t idx = base + (size_t)t * Cn;
        float kt = bf2f(K[idx]);
        float vt = bf2f(V[idx]);
        float ww2 = pp + w;
        float p2  = fmaxf(ww2, kt);
        float e1  = __expf(ww2 - p2);
        float e2  = __expf(kt - p2);
        aa = e1 * aa + e2 * vt;
        bb = e1 * bb + e2;
        pp = p2;
    }
    size_t o = ((size_t)b * NCH + j) * Cn + c;
    caa[o] = aa; cbb[o] = bb; cpp[o] = pp;
}

// ---------------- WKV pass2: scan over chunks (cheap, sequential) ----------
__global__ __launch_bounds__(256) void wkv_pass2(const float* __restrict__ Wd,
                                                 const float* __restrict__ caa,
                                                 const float* __restrict__ cbb,
                                                 const float* __restrict__ cpp,
                                                 float* __restrict__ saa,
                                                 float* __restrict__ sbb,
                                                 float* __restrict__ spp) {
    int c = blockIdx.x * 256 + threadIdx.x;
    int b = blockIdx.y;
    float Lw = -__expf(Wd[c]) * (float)LCH;
    float aa = 0.f, bb = 0.f, pp = -1e38f;
    for (int j = 0; j < NCH; ++j) {
        size_t o = ((size_t)b * NCH + j) * Cn + c;
        saa[o] = aa; sbb[o] = bb; spp[o] = pp;   // incoming state for chunk j
        float qa = caa[o], qb = cbb[o], qp = cpp[o];
        float ppd = pp + Lw;
        float p  = fmaxf(ppd, qp);
        float e1 = __expf(ppd - p);
        float e2 = __expf(qp - p);
        aa = e1 * aa + e2 * qa;
        bb = e1 * bb + e2 * qb;
        pp = p;
    }
}

// ---------------- WKV pass3: replay chunk with true state + gating --------
__global__ __launch_bounds__(256) void wkv_pass3(const unsigned short* __restrict__ K,
                                                 const unsigned short* __restrict__ V,
                                                 const unsigned short* __restrict__ Rb,
                                                 const float* __restrict__ Wd,
                                                 const float* __restrict__ Ud,
                                                 const float* __restrict__ saa,
                                                 const float* __restrict__ sbb,
                                                 const float* __restrict__ spp,
                                                 unsigned short* __restrict__ rwkv,
                                                 float* __restrict__ hidden) {
    int c = blockIdx.x * 256 + threadIdx.x;
    int j = blockIdx.y;
    int b = blockIdx.z;
    float w = -__expf(Wd[c]);
    float u = Ud[c];
    size_t o = ((size_t)b * NCH + j) * Cn + c;
    float aa = saa[o], bb = sbb[o], pp = spp[o];
    size_t base = ((size_t)(b * Tn + j * LCH)) * Cn + c;
    float y = 0.f;
#pragma unroll 4
    for (int t = 0; t < LCH; ++t) {
        size_t idx = base + (size_t)t * Cn;
        float kt = bf2f(K[idx]);
        float vt = bf2f(V[idx]);
        float rt = bf2f(Rb[idx]);
        float ww = u + kt;
        float p  = fmaxf(pp, ww);
        float e1 = __expf(pp - p);
        float e2 = __expf(ww - p);
        y = __fdividef(e1 * aa + e2 * vt, e1 * bb + e2);
        float sr = __fdividef(1.f, 1.f + __expf(-rt));
        rwkv[idx] = f2bf(sr * y);
        float ww2 = pp + w;
        float p2  = fmaxf(ww2, kt);
        float e1b = __expf(ww2 - p2);
        float e2b = __expf(kt - p2);
        aa = e1b * aa + e2b * vt;
        bb = e1b * bb + e2b;
        pp = p2;
    }
    if (j == NCH - 1) hidden[b * Cn + c] = y;
}

// ---------------- launcher ----------------
extern "C" void kernel_launch(void* const* d_in, const int* in_sizes, int n_in,
                              void* d_out, int out_size, void* d_ws, size_t ws_size,
                              hipStream_t stream) {
    const float* x   = (const float*)d_in[0];
    const float* Wd  = (const float*)d_in[1];
    const float* Ud  = (const float*)d_in[2];
    const float* tmk = (const float*)d_in[3];
    const float* tmv = (const float*)d_in[4];
    const float* tmr = (const float*)d_in[5];
    const float* Wk  = (const float*)d_in[6];
    const float* Wv  = (const float*)d_in[7];
    const float* Wr  = (const float*)d_in[8];
    const float* Wo  = (const float*)d_in[9];

    float* out    = (float*)d_out;
    float* hidden = out + (size_t)Mn * Cn;

    const size_t MK = (size_t)Mn * Cn;   // 16,777,216 elements
    const size_t CC = (size_t)Cn * Cn;   // 1,048,576 elements
    unsigned short* ak  = (unsigned short*)d_ws;   // [0, MK)
    unsigned short* av  = ak + MK;
    unsigned short* ar  = av + MK;
    unsigned short* Kb  = ar + MK;
    unsigned short* Wkb = Kb + MK;
    unsigned short* Wvb = Wkb + CC;
    unsigned short* Wrb = Wvb + CC;
    unsigned short* Wob = Wrb + CC;
    // overlays (safe by dataflow order):
    unsigned short* Vb = ak;   // ak dead after GEMM-K
    unsigned short* Rb = av;   // av dead after GEMM-V
    unsigned short* rw = ar;   // ar dead after GEMM-R
    // chunk-state arrays overlay Wkb/Wvb/Wrb (dead after their GEMMs):
    const size_t SB = (size_t)Bn * NCH * Cn;       // 262,144
    float* caa = (float*)Wkb;
    float* cbb = caa + SB;
    float* cpp = cbb + SB;
    float* saa = cpp + SB;
    float* sbb = saa + SB;
    float* spp = sbb + SB;

    cvt_kernel<<<dim3(CC / 1024), 256, 0, stream>>>(Wk, Wkb);
    cvt_kernel<<<dim3(CC / 1024), 256, 0, stream>>>(Wv, Wvb);
    cvt_kernel<<<dim3(CC / 1024), 256, 0, stream>>>(Wr, Wrb);
    cvt_kernel<<<dim3(CC / 1024), 256, 0, stream>>>(Wo, Wob);

    mix_kernel<<<dim3(MK / 1024), 256, 0, stream>>>(x, tmk, tmv, tmr, ak, av, ar);

    dim3 gg(Mn / 256, Cn / 256);   // (64, 4) = 256 blocks, 1 per CU
    gemm_bt<0><<<gg, 512, 0, stream>>>(ak, Wkb, Kb, nullptr);
    gemm_bt<0><<<gg, 512, 0, stream>>>(av, Wvb, Vb, nullptr);
    gemm_bt<0><<<gg, 512, 0, stream>>>(ar, Wrb, Rb, nullptr);

    dim3 gw(Cn / 256, NCH, Bn);    // (4, 32, 8)
    wkv_pass1<<<gw, 256, 0, stream>>>(Kb, Vb, Wd, caa, cbb, cpp);
    wkv_pass2<<<dim3(Cn / 256, Bn), 256, 0, stream>>>(Wd, caa, cbb, cpp, saa, sbb, spp);
    wkv_pass3<<<gw, 256, 0, stream>>>(Kb, Vb, Rb, Wd, Ud, saa, sbb, spp, rw, hidden);

    gemm_bt<1><<<gg, 512, 0, stream>>>(rw, Wob, nullptr, out);
}

// Round 11
// 351.012 us; speedup vs baseline: 3.3446x; 1.0322x over previous
//
#include <hip/hip_runtime.h>

#define Bn 8
#define Tn 2048
#define Cn 1024
#define Mn (Bn * Tn)   // 16384 rows
#define LCH 64
#define NCH (Tn / LCH) // 32 chunks

typedef __attribute__((ext_vector_type(8))) short short8;
typedef __attribute__((ext_vector_type(8))) unsigned short u16x8;
typedef __attribute__((ext_vector_type(4))) float f32x4;

typedef const __attribute__((address_space(1))) void gas_void;
typedef __attribute__((address_space(3))) void las_void;

__device__ __forceinline__ unsigned short f2bf(float f) {
    unsigned int u = __float_as_uint(f);
    u += 0x7FFFu + ((u >> 16) & 1u);   // round-to-nearest-even
    return (unsigned short)(u >> 16);
}
__device__ __forceinline__ float bf2f(unsigned short h) {
    return __uint_as_float(((unsigned int)h) << 16);
}

// ---------------- weight fp32 -> bf16 convert (all 4 in one launch) -------
__global__ __launch_bounds__(256) void cvt4_kernel(const float* __restrict__ s0,
                                                   const float* __restrict__ s1,
                                                   const float* __restrict__ s2,
                                                   const float* __restrict__ s3,
                                                   unsigned short* __restrict__ d0,
                                                   unsigned short* __restrict__ d1,
                                                   unsigned short* __restrict__ d2,
                                                   unsigned short* __restrict__ d3) {
    int i = blockIdx.x * 256 + threadIdx.x;           // over C*C/4 float4s
    int m = blockIdx.y;
    const float* src = (m == 0) ? s0 : (m == 1) ? s1 : (m == 2) ? s2 : s3;
    unsigned short* dst = (m == 0) ? d0 : (m == 1) ? d1 : (m == 2) ? d2 : d3;
    float4 v = ((const float4*)src)[i];
    ushort4 o;
    o.x = f2bf(v.x); o.y = f2bf(v.y); o.z = f2bf(v.z); o.w = f2bf(v.w);
    ((ushort4*)dst)[i] = o;
}

// ---------------- token shift + time-mix (3 outputs, bf16, 8 elem/thr) ----
__device__ __forceinline__ u16x8 mix8(const float4& a, const float4& b,
                                      const float4& sa, const float4& sb,
                                      const float4& ma, const float4& mb) {
    u16x8 o;
    o[0] = f2bf(sa.x + (a.x - sa.x) * ma.x);
    o[1] = f2bf(sa.y + (a.y - sa.y) * ma.y);
    o[2] = f2bf(sa.z + (a.z - sa.z) * ma.z);
    o[3] = f2bf(sa.w + (a.w - sa.w) * ma.w);
    o[4] = f2bf(sb.x + (b.x - sb.x) * mb.x);
    o[5] = f2bf(sb.y + (b.y - sb.y) * mb.y);
    o[6] = f2bf(sb.z + (b.z - sb.z) * mb.z);
    o[7] = f2bf(sb.w + (b.w - sb.w) * mb.w);
    return o;
}

__global__ __launch_bounds__(256) void mix_kernel(const float* __restrict__ x,
                                                  const float* __restrict__ tmk,
                                                  const float* __restrict__ tmv,
                                                  const float* __restrict__ tmr,
                                                  unsigned short* __restrict__ ak,
                                                  unsigned short* __restrict__ av,
                                                  unsigned short* __restrict__ ar) {
    int i = blockIdx.x * 256 + threadIdx.x;           // over Mn*Cn/8 groups
    int c8 = i & 127;                                  // Cn/8 = 128
    int t  = (i >> 7) & (Tn - 1);
    const float4* xp = (const float4*)x;
    float4 xa = xp[2 * i], xb = xp[2 * i + 1];
    float4 sa = make_float4(0.f, 0.f, 0.f, 0.f), sb = sa;
    if (t > 0) { sa = xp[2 * i - 256]; sb = xp[2 * i - 255]; }
    float4 ka = ((const float4*)tmk)[2 * c8], kb = ((const float4*)tmk)[2 * c8 + 1];
    float4 va = ((const float4*)tmv)[2 * c8], vb = ((const float4*)tmv)[2 * c8 + 1];
    float4 ra = ((const float4*)tmr)[2 * c8], rb = ((const float4*)tmr)[2 * c8 + 1];
    ((u16x8*)ak)[i] = mix8(xa, xb, sa, sb, ka, kb);
    ((u16x8*)av)[i] = mix8(xa, xb, sa, sb, va, vb);
    ((u16x8*)ar)[i] = mix8(xa, xb, sa, sb, ra, rb);
}

// ======================= bf16 NT GEMM, 256x256 read-ahead pipeline =========
// C[m,n] = sum_k A[m,k]*B[n,k].  M=16384, N=1024, K=1024.
// BM=BN=256, BK=32. 8 waves (2M x 4N), wave-tile 128x64 (acc 8x4).
// 4 LDS buffers x 32KB = 128KB. Stage 3 tiles ahead; per-tile sync =
// vmcnt(4) (4 gloads/wave/tile), never 0 until tail. Full fragment
// double-buffer: ALL of tile t+1's 12 frags read during tile t.
// 2 phases/tile, 16-MFMA setprio clusters.
// Swizzle: phys_slot = q ^ ((row>>1)&3), via pre-swizzled global source
// (linear gload_lds dest) + same XOR on ds_read; 2 lanes/bank (free).

#define BKg  32
#define NTg  32                    // K / BKg
#define ABYT (256 * BKg * 2)       // 16384 bytes (A region per buffer)
#define BUFBY (2 * ABYT)           // 32768 bytes per buffer

#define PHASE_BAR() asm volatile("s_barrier" ::: "memory")
#define WAITV4()    asm volatile("s_waitcnt vmcnt(4)" ::: "memory")
#define WAITV0()    asm volatile("s_waitcnt vmcnt(0)" ::: "memory")

// stage one 16-row x 32-col group (1KB): gbase -> row0,k0 of the group;
// LDS dest linear (row*64 bytes); source column slot pre-swizzled.
__device__ __forceinline__ void stage16(const unsigned short* gbase,
                                        char* ldsdst, int lane) {
    int r = lane >> 2;
    int g = (lane & 3) ^ ((lane >> 3) & 3);   // inverse swizzle on source
    const unsigned short* src = gbase + (size_t)r * 1024 + g * 8;
    __builtin_amdgcn_global_load_lds((gas_void*)src, (las_void*)ldsdst, 16, 0, 0);
}

__device__ __forceinline__ void gemm_body(int t,
    const unsigned short* __restrict__ A, const unsigned short* __restrict__ Bw,
    char* lds, int bm, int bn, int lane, int wid, int wr, int wc, int lr, int rsw,
    short8* afc, short8* bfc, short8* afn, short8* bfn, f32x4 acc[8][4]) {
    char* An = lds + (size_t)((t + 3) & 3) * BUFBY;    // stage target
    char* Bs = An + ABYT;
    char* A1 = lds + (size_t)((t + 1) & 3) * BUFBY;    // read-ahead source
    char* B1 = A1 + ABYT;
    const bool st = (t + 3) < NTg;
    const bool ra = (t + 1) < NTg;
    const int k0 = (t + 3) * BKg;

    // ---- Ph0: stage A(t+3) both halves; read bfn[0..3]+afn[0..3] (buf t+1);
    //          16 MFMA (mi 0..3)
    if (st) {
        stage16(A + (size_t)(bm + wid * 16) * 1024 + k0,       An + wid * 16 * 64, lane);
        stage16(A + (size_t)(bm + 128 + wid * 16) * 1024 + k0, An + (128 + wid * 16) * 64, lane);
    }
    if (ra) {
#pragma unroll
        for (int ni = 0; ni < 4; ++ni)
            bfn[ni] = *(const short8*)(B1 + (wc * 64 + ni * 16 + lr) * 64 + rsw);
#pragma unroll
        for (int mi = 0; mi < 4; ++mi)
            afn[mi] = *(const short8*)(A1 + (wr * 128 + mi * 16 + lr) * 64 + rsw);
    }
    __builtin_amdgcn_s_setprio(1);
#pragma unroll
    for (int mi = 0; mi < 4; ++mi)
#pragma unroll
        for (int ni = 0; ni < 4; ++ni)
            acc[mi][ni] = __builtin_amdgcn_mfma_f32_16x16x32_bf16(afc[mi], bfc[ni], acc[mi][ni], 0, 0, 0);
    __builtin_amdgcn_s_setprio(0);
    PHASE_BAR();

    // ---- Ph1: stage B(t+3) both halves; read afn[4..7]; 16 MFMA (mi 4..7);
    //          counted sync
    if (st) {
        stage16(Bw + (size_t)(bn + wid * 16) * 1024 + k0,       Bs + wid * 16 * 64, lane);
        stage16(Bw + (size_t)(bn + 128 + wid * 16) * 1024 + k0, Bs + (128 + wid * 16) * 64, lane);
    }
    if (ra) {
#pragma unroll
        for (int mi = 4; mi < 8; ++mi)
            afn[mi] = *(const short8*)(A1 + (wr * 128 + mi * 16 + lr) * 64 + rsw);
    }
    __builtin_amdgcn_s_setprio(1);
#pragma unroll
    for (int mi = 4; mi < 8; ++mi)
#pragma unroll
        for (int ni = 0; ni < 4; ++ni)
            acc[mi][ni] = __builtin_amdgcn_mfma_f32_16x16x32_bf16(afc[mi], bfc[ni], acc[mi][ni], 0, 0, 0);
    __builtin_amdgcn_s_setprio(0);
    if (st) { WAITV4(); } else { WAITV0(); }
    PHASE_BAR();
}

template <int FOUT>   // 0: bf16 out, 1: fp32 out
__global__ __launch_bounds__(512, 2) void gemm_bt(const unsigned short* __restrict__ A,
                                                  const unsigned short* __restrict__ Bw,
                                                  unsigned short* __restrict__ Cb,
                                                  float* __restrict__ Cf) {
    __shared__ char lds[4 * BUFBY];     // 128 KB
    const int tid  = threadIdx.x;
    const int lane = tid & 63;
    const int wid  = tid >> 6;          // 0..7
    const int wr   = wid >> 2;          // 0..1 (M half)
    const int wc   = wid & 3;           // 0..3 (N quarter)
    const int bm   = blockIdx.x * 256;
    const int bn   = blockIdx.y * 256;

    const int lr  = lane & 15;
    const int rsw = (((lane >> 4) ^ ((lane >> 1) & 3)) << 4);

    f32x4 acc[8][4] = {};
    short8 afA[8], bfA[4], afB[8], bfB[4];

    // ---- prologue: stage tiles 0,1,2 (bufs 0,1,2) ----
#pragma unroll
    for (int i = 0; i < 3; ++i) {
        char* Ad = lds + (size_t)i * BUFBY;
        int k0 = i * BKg;
        stage16(A  + (size_t)(bm + wid * 16) * 1024 + k0,       Ad + wid * 16 * 64, lane);
        stage16(A  + (size_t)(bm + 128 + wid * 16) * 1024 + k0, Ad + (128 + wid * 16) * 64, lane);
        stage16(Bw + (size_t)(bn + wid * 16) * 1024 + k0,       Ad + ABYT + wid * 16 * 64, lane);
        stage16(Bw + (size_t)(bn + 128 + wid * 16) * 1024 + k0, Ad + ABYT + (128 + wid * 16) * 64, lane);
    }
    WAITV4();        // bufs 0,1 landed (buf 2's 4 loads may float)
    PHASE_BAR();

    // tile-0 fragments: full set
#pragma unroll
    for (int mi = 0; mi < 8; ++mi)
        afA[mi] = *(const short8*)(lds + (wr * 128 + mi * 16 + lr) * 64 + rsw);
#pragma unroll
    for (int ni = 0; ni < 4; ++ni)
        bfA[ni] = *(const short8*)(lds + ABYT + (wc * 64 + ni * 16 + lr) * 64 + rsw);

#pragma unroll 1
    for (int t = 0; t < NTg; t += 2) {
        gemm_body(t,     A, Bw, lds, bm, bn, lane, wid, wr, wc, lr, rsw, afA, bfA, afB, bfB, acc);
        gemm_body(t + 1, A, Bw, lds, bm, bn, lane, wid, wr, wc, lr, rsw, afB, bfB, afA, bfA, acc);
    }

    // ---- epilogue: C/D layout col=lane&15, row=(lane>>4)*4+reg ----
    const int crow0 = bm + wr * 128 + (lane >> 4) * 4;
    const int ccol0 = bn + wc * 64 + lr;
#pragma unroll
    for (int mi = 0; mi < 8; ++mi) {
#pragma unroll
        for (int ni = 0; ni < 4; ++ni) {
            int col = ccol0 + ni * 16;
#pragma unroll
            for (int j = 0; j < 4; ++j) {
                size_t idx = (size_t)(crow0 + mi * 16 + j) * 1024 + col;
                float v = acc[mi][ni][j];
                if (FOUT) Cf[idx] = v;
                else      Cb[idx] = f2bf(v);
            }
        }
    }
}

// ---------------- WKV pass1: per-chunk local contributions ----------------
__global__ __launch_bounds__(256) void wkv_pass1(const unsigned short* __restrict__ K,
                                                 const unsigned short* __restrict__ V,
                                                 const float* __restrict__ Wd,
                                                 float* __restrict__ caa,
                                                 float* __restrict__ cbb,
                                                 float* __restrict__ cpp) {
    int c = blockIdx.x * 256 + threadIdx.x;   // 0..1023
    int j = blockIdx.y;                        // chunk 0..NCH-1
    int b = blockIdx.z;                        // 0..7
    float w = -__expf(Wd[c]);
    float aa = 0.f, bb = 0.f, pp = -1e38f;
    size_t base = ((size_t)(b * Tn + j * LCH)) * Cn + c;
#pragma unroll 4
    for (int t = 0; t < LCH; ++t) {
        size_t idx = base + (size_t)t * Cn;
        float kt = bf2f(K[idx]);
        float vt = bf2f(V[idx]);
        float ww2 = pp + w;
        float p2  = fmaxf(ww2, kt);
        float e1  = __expf(ww2 - p2);
        float e2  = __expf(kt - p2);
        aa = e1 * aa + e2 * vt;
        bb = e1 * bb + e2;
        pp = p2;
    }
    size_t o = ((size_t)b * NCH + j) * Cn + c;
    caa[o] = aa; cbb[o] = bb; cpp[o] = pp;
}

// ---------------- WKV pass2: scan over chunks (cheap, sequential) ----------
__global__ __launch_bounds__(256) void wkv_pass2(const float* __restrict__ Wd,
                                                 const float* __restrict__ caa,
                                                 const float* __restrict__ cbb,
                                                 const float* __restrict__ cpp,
                                                 float* __restrict__ saa,
                                                 float* __restrict__ sbb,
                                                 float* __restrict__ spp) {
    int c = blockIdx.x * 256 + threadIdx.x;
    int b = blockIdx.y;
    float Lw = -__expf(Wd[c]) * (float)LCH;
    float aa = 0.f, bb = 0.f, pp = -1e38f;
    for (int j = 0; j < NCH; ++j) {
        size_t o = ((size_t)b * NCH + j) * Cn + c;
        saa[o] = aa; sbb[o] = bb; spp[o] = pp;   // incoming state for chunk j
        float qa = caa[o], qb = cbb[o], qp = cpp[o];
        float ppd = pp + Lw;
        float p  = fmaxf(ppd, qp);
        float e1 = __expf(ppd - p);
        float e2 = __expf(qp - p);
        aa = e1 * aa + e2 * qa;
        bb = e1 * bb + e2 * qb;
        pp = p;
    }
}

// ---------------- WKV pass3: replay chunk with true state + gating --------
__global__ __launch_bounds__(256) void wkv_pass3(const unsigned short* __restrict__ K,
                                                 const unsigned short* __restrict__ V,
                                                 const unsigned short* __restrict__ Rb,
                                                 const float* __restrict__ Wd,
                                                 const float* __restrict__ Ud,
                                                 const float* __restrict__ saa,
                                                 const float* __restrict__ sbb,
                                                 const float* __restrict__ spp,
                                                 unsigned short* __restrict__ rwkv,
                                                 float* __restrict__ hidden) {
    int c = blockIdx.x * 256 + threadIdx.x;
    int j = blockIdx.y;
    int b = blockIdx.z;
    float w = -__expf(Wd[c]);
    float u = Ud[c];
    size_t o = ((size_t)b * NCH + j) * Cn + c;
    float aa = saa[o], bb = sbb[o], pp = spp[o];
    size_t base = ((size_t)(b * Tn + j * LCH)) * Cn + c;
    float y = 0.f;
#pragma unroll 4
    for (int t = 0; t < LCH; ++t) {
        size_t idx = base + (size_t)t * Cn;
        float kt = bf2f(K[idx]);
        float vt = bf2f(V[idx]);
        float rt = bf2f(Rb[idx]);
        float ww = u + kt;
        float p  = fmaxf(pp, ww);
        float e1 = __expf(pp - p);
        float e2 = __expf(ww - p);
        y = __fdividef(e1 * aa + e2 * vt, e1 * bb + e2);
        float sr = __fdividef(1.f, 1.f + __expf(-rt));
        rwkv[idx] = f2bf(sr * y);
        float ww2 = pp + w;
        float p2  = fmaxf(ww2, kt);
        float e1b = __expf(ww2 - p2);
        float e2b = __expf(kt - p2);
        aa = e1b * aa + e2b * vt;
        bb = e1b * bb + e2b;
        pp = p2;
    }
    if (j == NCH - 1) hidden[b * Cn + c] = y;
}

// ---------------- launcher ----------------
extern "C" void kernel_launch(void* const* d_in, const int* in_sizes, int n_in,
                              void* d_out, int out_size, void* d_ws, size_t ws_size,
                              hipStream_t stream) {
    const float* x   = (const float*)d_in[0];
    const float* Wd  = (const float*)d_in[1];
    const float* Ud  = (const float*)d_in[2];
    const float* tmk = (const float*)d_in[3];
    const float* tmv = (const float*)d_in[4];
    const float* tmr = (const float*)d_in[5];
    const float* Wk  = (const float*)d_in[6];
    const float* Wv  = (const float*)d_in[7];
    const float* Wr  = (const float*)d_in[8];
    const float* Wo  = (const float*)d_in[9];

    float* out    = (float*)d_out;
    float* hidden = out + (size_t)Mn * Cn;

    const size_t MK = (size_t)Mn * Cn;   // 16,777,216 elements
    const size_t CC = (size_t)Cn * Cn;   // 1,048,576 elements
    unsigned short* ak  = (unsigned short*)d_ws;   // [0, MK)
    unsigned short* av  = ak + MK;
    unsigned short* ar  = av + MK;
    unsigned short* Kb  = ar + MK;
    unsigned short* Wkb = Kb + MK;
    unsigned short* Wvb = Wkb + CC;
    unsigned short* Wrb = Wvb + CC;
    unsigned short* Wob = Wrb + CC;
    // overlays (safe by dataflow order):
    unsigned short* Vb = ak;   // ak dead after GEMM-K
    unsigned short* Rb = av;   // av dead after GEMM-V
    unsigned short* rw = ar;   // ar dead after GEMM-R
    // chunk-state arrays overlay Wkb/Wvb/Wrb (dead after their GEMMs):
    const size_t SB = (size_t)Bn * NCH * Cn;       // 262,144
    float* caa = (float*)Wkb;
    float* cbb = caa + SB;
    float* cpp = cbb + SB;
    float* saa = cpp + SB;
    float* sbb = saa + SB;
    float* spp = sbb + SB;

    cvt4_kernel<<<dim3(CC / 1024, 4), 256, 0, stream>>>(Wk, Wv, Wr, Wo, Wkb, Wvb, Wrb, Wob);

    mix_kernel<<<dim3(MK / 2048), 256, 0, stream>>>(x, tmk, tmv, tmr, ak, av, ar);

    dim3 gg(Mn / 256, Cn / 256);   // (64, 4) = 256 blocks, 1 per CU
    gemm_bt<0><<<gg, 512, 0, stream>>>(ak, Wkb, Kb, nullptr);
    gemm_bt<0><<<gg, 512, 0, stream>>>(av, Wvb, Vb, nullptr);
    gemm_bt<0><<<gg, 512, 0, stream>>>(ar, Wrb, Rb, nullptr);

    dim3 gw(Cn / 256, NCH, Bn);    // (4, 32, 8)
    wkv_pass1<<<gw, 256, 0, stream>>>(Kb, Vb, Wd, caa, cbb, cpp);
    wkv_pass2<<<dim3(Cn / 256, Bn), 256, 0, stream>>>(Wd, caa, cbb, cpp, saa, sbb, spp);
    wkv_pass3<<<gw, 256, 0, stream>>>(Kb, Vb, Rb, Wd, Ud, saa, sbb, spp, rw, hidden);

    gemm_bt<1><<<gg, 512, 0, stream>>>(rw, Wob, nullptr, out);
}